// Round 5
// baseline (1183.364 us; speedup 1.0000x reference)
//
#include <hip/hip_runtime.h>
#include <math.h>

#define FDIM 64
#define HDIM 128
#define RPW  16              // edges (rows) per wave
#define WPB  4               // waves per block
#define EPB  (RPW*WPB)       // edges per block = 64
#define STRIDE 192           // LDS row stride (floats): cols 0..63 + 64..191

__device__ __forceinline__ float gelu_exact(float x){
    return 0.5f * x * (1.0f + erff(x * 0.70710678118654752440f));
}

__global__ __launch_bounds__(256, 3)
void arn_kernel(const float* __restrict__ known_mask,   // [N_SAMP,64] f32
                const int* __restrict__ obs_idx,        // [E] i32
                const int* __restrict__ obs_mask_idx,   // [E] i32
                const int* __restrict__ attr_idx,       // [E] i32
                const float* __restrict__ obs_embs,     // [N_OBS,128] f32
                const float* __restrict__ fea_corr,     // [64,64] f32
                const float* __restrict__ W_rm1, const float* __restrict__ b_rm1,  // [64,128],[128]
                const float* __restrict__ W_rm2, const float* __restrict__ b_rm2,  // [128,64],[64]
                const float* __restrict__ W_rr,  const float* __restrict__ b_rr,   // [64,128],[128]
                const float* __restrict__ W_rc,  const float* __restrict__ b_rc,   // [128,128],[128]
                float2* __restrict__ out2, int E)       // [E,128] f32 as float2
{
    __shared__ __align__(16) float buf[WPB][RPW][STRIDE];
    __shared__ int sAttr[WPB][RPW];
    __shared__ int sObs[WPB][RPW];

    const int wave = threadIdx.x >> 6;
    const int lane = threadIdx.x & 63;
    const long long ebase = ((long long)blockIdx.x * WPB + wave) * RPW;

    float (*X)[STRIDE] = buf[wave];

    // ---------- stage 0: gather mask row, apply self-mask, softmax -> S at cols 0..63 ----------
    #pragma unroll 1
    for (int r = 0; r < RPW; ++r){
        long long e = ebase + r;
        int ec = (e < (long long)E) ? (int)e : (E - 1);
        int attr = attr_idx[ec];
        int mrow = obs_mask_idx[ec];
        if (lane == 0){ sAttr[wave][r] = attr; sObs[wave][r] = obs_idx[ec]; }
        float v = known_mask[(long long)mrow * FDIM + lane];
        if (lane == attr) v = 0.f;
        float mx = v;
        #pragma unroll
        for (int off = 32; off; off >>= 1) mx = fmaxf(mx, __shfl_xor(mx, off));
        float ex = expf(v - mx);
        float s = ex;
        #pragma unroll
        for (int off = 32; off; off >>= 1) s += __shfl_xor(s, off);
        X[r][lane] = ex / s;
    }

    // ---------- GEMM1: S[16,64] @ W_rm1[64,128] + b -> gelu -> h1 at cols 64..191 ----------
    {
        const float2* W = (const float2*)W_rm1;
        float acc[RPW][2];
        #pragma unroll
        for (int r = 0; r < RPW; ++r){ acc[r][0] = 0.f; acc[r][1] = 0.f; }
        #pragma unroll 2
        for (int k0 = 0; k0 < FDIM; k0 += 4){
            float2 w0 = W[(k0+0)*(HDIM/2) + lane];
            float2 w1 = W[(k0+1)*(HDIM/2) + lane];
            float2 w2 = W[(k0+2)*(HDIM/2) + lane];
            float2 w3 = W[(k0+3)*(HDIM/2) + lane];
            #pragma unroll
            for (int r = 0; r < RPW; ++r){
                float4 x = *(const float4*)&X[r][k0];
                acc[r][0] = fmaf(x.w,w3.x,fmaf(x.z,w2.x,fmaf(x.y,w1.x,fmaf(x.x,w0.x,acc[r][0]))));
                acc[r][1] = fmaf(x.w,w3.y,fmaf(x.z,w2.y,fmaf(x.y,w1.y,fmaf(x.x,w0.y,acc[r][1]))));
            }
        }
        float2 bb = ((const float2*)b_rm1)[lane];
        #pragma unroll
        for (int r = 0; r < RPW; ++r){
            X[r][FDIM + 2*lane]     = gelu_exact(acc[r][0] + bb.x);
            X[r][FDIM + 2*lane + 1] = gelu_exact(acc[r][1] + bb.y);
        }
    }

    // ---------- GEMM2: h1[16,128] @ W_rm2[128,64] + b -> gelu -> *fea_corr[attr] -> t at cols 0..63 ----------
    {
        float acc[RPW];
        #pragma unroll
        for (int r = 0; r < RPW; ++r) acc[r] = 0.f;
        #pragma unroll 2
        for (int k0 = 0; k0 < HDIM; k0 += 4){
            float w0 = W_rm2[(k0+0)*FDIM + lane];
            float w1 = W_rm2[(k0+1)*FDIM + lane];
            float w2 = W_rm2[(k0+2)*FDIM + lane];
            float w3 = W_rm2[(k0+3)*FDIM + lane];
            #pragma unroll
            for (int r = 0; r < RPW; ++r){
                float4 x = *(const float4*)&X[r][FDIM + k0];
                acc[r] = fmaf(x.w,w3,fmaf(x.z,w2,fmaf(x.y,w1,fmaf(x.x,w0,acc[r]))));
            }
        }
        float b2 = b_rm2[lane];
        #pragma unroll
        for (int r = 0; r < RPW; ++r){
            float m2v = gelu_exact(acc[r] + b2);
            float fc  = fea_corr[sAttr[wave][r]*FDIM + lane];
            X[r][lane] = m2v * fc;
        }
    }

    // ---------- GEMM3: t[16,64] @ W_rr[64,128] + b -> gelu -> * obs_h -> u at cols 64..191 ----------
    {
        const float2* W = (const float2*)W_rr;
        float acc[RPW][2];
        #pragma unroll
        for (int r = 0; r < RPW; ++r){ acc[r][0] = 0.f; acc[r][1] = 0.f; }
        #pragma unroll 2
        for (int k0 = 0; k0 < FDIM; k0 += 4){
            float2 w0 = W[(k0+0)*(HDIM/2) + lane];
            float2 w1 = W[(k0+1)*(HDIM/2) + lane];
            float2 w2 = W[(k0+2)*(HDIM/2) + lane];
            float2 w3 = W[(k0+3)*(HDIM/2) + lane];
            #pragma unroll
            for (int r = 0; r < RPW; ++r){
                float4 x = *(const float4*)&X[r][k0];
                acc[r][0] = fmaf(x.w,w3.x,fmaf(x.z,w2.x,fmaf(x.y,w1.x,fmaf(x.x,w0.x,acc[r][0]))));
                acc[r][1] = fmaf(x.w,w3.y,fmaf(x.z,w2.y,fmaf(x.y,w1.y,fmaf(x.x,w0.y,acc[r][1]))));
            }
        }
        float2 bb = ((const float2*)b_rr)[lane];
        #pragma unroll
        for (int r = 0; r < RPW; ++r){
            float2 oh = ((const float2*)obs_embs)[(long long)sObs[wave][r]*(HDIM/2) + lane];
            X[r][FDIM + 2*lane]     = oh.x * gelu_exact(acc[r][0] + bb.x);
            X[r][FDIM + 2*lane + 1] = oh.y * gelu_exact(acc[r][1] + bb.y);
        }
    }

    // ---------- GEMM4: u[16,128] @ W_rc[128,128] + b -> gelu -> out (f32) ----------
    {
        const float2* W = (const float2*)W_rc;
        float acc[RPW][2];
        #pragma unroll
        for (int r = 0; r < RPW; ++r){ acc[r][0] = 0.f; acc[r][1] = 0.f; }
        #pragma unroll 2
        for (int k0 = 0; k0 < HDIM; k0 += 4){
            float2 w0 = W[(k0+0)*(HDIM/2) + lane];
            float2 w1 = W[(k0+1)*(HDIM/2) + lane];
            float2 w2 = W[(k0+2)*(HDIM/2) + lane];
            float2 w3 = W[(k0+3)*(HDIM/2) + lane];
            #pragma unroll
            for (int r = 0; r < RPW; ++r){
                float4 x = *(const float4*)&X[r][FDIM + k0];
                acc[r][0] = fmaf(x.w,w3.x,fmaf(x.z,w2.x,fmaf(x.y,w1.x,fmaf(x.x,w0.x,acc[r][0]))));
                acc[r][1] = fmaf(x.w,w3.y,fmaf(x.z,w2.y,fmaf(x.y,w1.y,fmaf(x.x,w0.y,acc[r][1]))));
            }
        }
        float2 bb = ((const float2*)b_rc)[lane];
        #pragma unroll
        for (int r = 0; r < RPW; ++r){
            long long e = ebase + r;
            if (e < (long long)E){
                float2 y;
                y.x = gelu_exact(acc[r][0] + bb.x);
                y.y = gelu_exact(acc[r][1] + bb.y);
                out2[e*(HDIM/2) + lane] = y;
            }
        }
    }
}

extern "C" void kernel_launch(void* const* d_in, const int* in_sizes, int n_in,
                              void* d_out, int out_size, void* d_ws, size_t ws_size,
                              hipStream_t stream)
{
    (void)n_in; (void)out_size; (void)d_ws; (void)ws_size;
    const float* known_mask   = (const float*)d_in[0];
    const int*   obs_idx      = (const int*)d_in[1];
    const int*   obs_mask_idx = (const int*)d_in[2];
    const int*   attr_idx     = (const int*)d_in[3];
    const float* obs_embs     = (const float*)d_in[4];
    const float* fea_corr     = (const float*)d_in[5];
    const float* W_rm1 = (const float*)d_in[6];
    const float* b_rm1 = (const float*)d_in[7];
    const float* W_rm2 = (const float*)d_in[8];
    const float* b_rm2 = (const float*)d_in[9];
    const float* W_rr  = (const float*)d_in[10];
    const float* b_rr  = (const float*)d_in[11];
    const float* W_rc  = (const float*)d_in[12];
    const float* b_rc  = (const float*)d_in[13];
    float2* out2 = (float2*)d_out;

    const int E = in_sizes[1];
    const int blocks = (E + EPB - 1) / EPB;
    hipLaunchKernelGGL(arn_kernel, dim3(blocks), dim3(256), 0, stream,
                       known_mask, obs_idx, obs_mask_idx, attr_idx,
                       obs_embs, fea_corr,
                       W_rm1, b_rm1, W_rm2, b_rm2,
                       W_rr, b_rr, W_rc, b_rc,
                       out2, E);
}